// Round 1
// baseline (230.994 us; speedup 1.0000x reference)
//
#include <hip/hip_runtime.h>
#include <cstdint>

typedef __attribute__((ext_vector_type(8))) short s16x8;
typedef __attribute__((ext_vector_type(4))) float f32x4;

#define L2E 1.44269504088896340736f

__device__ __forceinline__ short f2bf(float f) {
  union { float f; unsigned u; } v; v.f = f;
  unsigned r = (v.u + 0x7fffu + ((v.u >> 16) & 1u)) >> 16;
  return (short)r;
}

typedef const __attribute__((address_space(1))) unsigned int* gas_p;
typedef __attribute__((address_space(3))) unsigned int* las_p;
__device__ __forceinline__ void stage16(const void* g, void* l) {
  __builtin_amdgcn_global_load_lds((gas_p)(uintptr_t)g,
                                   (las_p)(unsigned int)(uintptr_t)l, 16, 0, 0);
}

// ---------------- fp32 -> bf16 convert (x) ----------------
__global__ __launch_bounds__(256) void cvt_bf16(const float* __restrict__ in,
                                                short* __restrict__ out) {
  int i = blockIdx.x * 256 + threadIdx.x;          // 524288 threads, 8 elems each
  const f32x4* p = (const f32x4*)in + (size_t)i * 2;
  f32x4 a = p[0], b = p[1];
  s16x8 o;
  o[0] = f2bf(a[0]); o[1] = f2bf(a[1]); o[2] = f2bf(a[2]); o[3] = f2bf(a[3]);
  o[4] = f2bf(b[0]); o[5] = f2bf(b[1]); o[6] = f2bf(b[2]); o[7] = f2bf(b[3]);
  *((s16x8*)out + i) = o;
}

// ------------- transpose 1024x1024 fp32 -> bf16 [N][K] -------------
__global__ __launch_bounds__(256) void transpose_w(const float* __restrict__ in,
                                                   short* __restrict__ out) {
  __shared__ float tile[64][65];
  const int bi = blockIdx.y, bj = blockIdx.x;
  const int t = threadIdx.x;
  const int c = t & 63, r0 = t >> 6;
#pragma unroll
  for (int i = 0; i < 16; i++) {
    int r = r0 + i * 4;
    tile[r][c] = in[(size_t)(bi * 64 + r) * 1024 + bj * 64 + c];
  }
  __syncthreads();
#pragma unroll
  for (int i = 0; i < 16; i++) {
    int r = r0 + i * 4;  // out[n][k] = in[k][n]
    out[(size_t)(bj * 64 + r) * 1024 + bi * 64 + c] = f2bf(tile[c][r]);
  }
}

// ---------------- GEMM: C[M,N] = A[M,K] * B[N,K]^T, bf16 in, fp32 acc ----------------
// EPI 0: fused QKV epilogue -> Q[B,H,T,D], K[B,H,T,D], V^T[B,H,D,T] bf16 (+bias)
// EPI 1: fp32 out row-major [M][N] (+bias)
template <int EPI>
__global__ __launch_bounds__(256) void gemm_bt(
    const short* __restrict__ A, const short* __restrict__ B, int N, int K,
    const float* __restrict__ b0, const float* __restrict__ b1,
    const float* __restrict__ b2, short* __restrict__ o0, short* __restrict__ o1,
    short* __restrict__ o2, float* __restrict__ ofp) {
  __shared__ short As[128 * 32];
  __shared__ short Bs[128 * 32];
  const int tid = threadIdx.x;
  const int lane = tid & 63;
  const int wave = tid >> 6;
  const int wr = wave >> 1, wc = wave & 1;
  const int l15 = lane & 15, l4 = lane >> 4;
  const int m0 = blockIdx.y * 128, n0 = blockIdx.x * 128;
  const short* Ab = A + (size_t)m0 * K;
  const short* Bb = B + (size_t)n0 * K;
  f32x4 acc[4][4];
#pragma unroll
  for (int i = 0; i < 4; i++)
#pragma unroll
    for (int j = 0; j < 4; j++) acc[i][j] = (f32x4){0.f, 0.f, 0.f, 0.f};

  const int srow = tid >> 2;  // 0..63
  const int sch = tid & 3;    // 16B chunk within 64B row
  for (int k0 = 0; k0 < K; k0 += 32) {
    stage16(Ab + (size_t)srow * K + k0 + sch * 8, As + tid * 8);
    stage16(Ab + (size_t)(srow + 64) * K + k0 + sch * 8, As + 2048 + tid * 8);
    stage16(Bb + (size_t)srow * K + k0 + sch * 8, Bs + tid * 8);
    stage16(Bb + (size_t)(srow + 64) * K + k0 + sch * 8, Bs + 2048 + tid * 8);
    __syncthreads();
    s16x8 af[4], bfr[4];
#pragma unroll
    for (int i = 0; i < 4; i++) {
      af[i] = *(const s16x8*)(As + (wr * 64 + i * 16 + l15) * 32 + l4 * 8);
      bfr[i] = *(const s16x8*)(Bs + (wc * 64 + i * 16 + l15) * 32 + l4 * 8);
    }
#pragma unroll
    for (int mi = 0; mi < 4; mi++)
#pragma unroll
      for (int ni = 0; ni < 4; ni++)
        acc[mi][ni] = __builtin_amdgcn_mfma_f32_16x16x32_bf16(af[mi], bfr[ni],
                                                              acc[mi][ni], 0, 0, 0);
    __syncthreads();
  }

#pragma unroll
  for (int ni = 0; ni < 4; ni++) {
    const int col = n0 + wc * 64 + ni * 16 + l15;
    if (EPI == 1) {
      const float bias = b0[col];
#pragma unroll
      for (int mi = 0; mi < 4; mi++)
#pragma unroll
        for (int r = 0; r < 4; r++) {
          int row = m0 + wr * 64 + mi * 16 + l4 * 4 + r;
          ofp[(size_t)row * N + col] = acc[mi][ni][r] + bias;
        }
    } else {
      const float* bp; short* dst; int c1; int isV = 0;
      if (col < 1024) { bp = b0; dst = o0; c1 = col; }
      else if (col < 2048) { bp = b1; dst = o1; c1 = col - 1024; }
      else { bp = b2; dst = o2; c1 = col - 2048; isV = 1; }
      const float bias = bp[c1];
      const int h = c1 >> 6, d = c1 & 63;
#pragma unroll
      for (int mi = 0; mi < 4; mi++)
#pragma unroll
        for (int r = 0; r < 4; r++) {
          int row = m0 + wr * 64 + mi * 16 + l4 * 4 + r;
          int bb = row >> 11, t = row & 2047;
          float v = acc[mi][ni][r] + bias;
          size_t idx = isV ? ((size_t)((bb * 16 + h) * 64 + d) * 2048 + t)
                           : ((size_t)((bb * 16 + h) * 2048 + t) * 64 + d);
          dst[idx] = f2bf(v);
        }
    }
  }
}

// ---------------- causal flash attention, QBLK=64, KVBLK=64, D=64 ----------------
__global__ __launch_bounds__(256) void attn64(const short* __restrict__ Q,
                                              const short* __restrict__ K,
                                              const short* __restrict__ Vt,
                                              short* __restrict__ Y) {
  __shared__ short Ks[64 * 64];      // [tk][d] swizzled (chunk ^ row&7)
  __shared__ short Vs[64 * 64];      // [d][tk] swizzled
  __shared__ short Ps[4][16 * 64];   // per-wave P [q16][tk64] swizzled
  const int bh = blockIdx.y;
  const int qt = gridDim.x - 1 - blockIdx.x;  // heavy blocks first
  const int q0 = qt * 64;
  const int tid = threadIdx.x, lane = tid & 63, wave = tid >> 6;
  const int l15 = lane & 15, l4 = lane >> 4;
  const short* Qp = Q + (size_t)bh * 2048 * 64;
  const short* Kp = K + (size_t)bh * 2048 * 64;
  const short* Vp = Vt + (size_t)bh * 64 * 2048;

  const int qrow = q0 + wave * 16 + l15;  // A-frag row for this lane
  s16x8 qf[2];
  qf[0] = *(const s16x8*)(Qp + (size_t)qrow * 64 + l4 * 8);
  qf[1] = *(const s16x8*)(Qp + (size_t)qrow * 64 + 32 + l4 * 8);

  float m_r[4], l_r[4];
  f32x4 acc_o[4];
#pragma unroll
  for (int r = 0; r < 4; r++) { m_r[r] = -__builtin_inff(); l_r[r] = 0.f; }
#pragma unroll
  for (int j = 0; j < 4; j++) acc_o[j] = (f32x4){0.f, 0.f, 0.f, 0.f};

  const int srow = tid >> 3;  // staging: 0..31 (+32 second issue)
  const int sch0 = tid & 7;

  for (int kt = 0; kt <= qt; kt++) {
    const int k0 = kt * 64;
    // stage K and V^T tiles, pre-swizzled global source so LDS holds chunk^(row&7)
#pragma unroll
    for (int i = 0; i < 2; i++) {
      int row = srow + i * 32;
      int ch = sch0;
      int sc = ch ^ (row & 7);
      stage16(Kp + (size_t)(k0 + row) * 64 + sc * 8, Ks + row * 64 + ch * 8);
      stage16(Vp + (size_t)row * 2048 + k0 + sc * 8, Vs + row * 64 + ch * 8);
    }
    __syncthreads();

    // S = (Q K^T) * 0.125
    f32x4 sv[4];
#pragma unroll
    for (int ni = 0; ni < 4; ni++) {
      f32x4 s = (f32x4){0.f, 0.f, 0.f, 0.f};
#pragma unroll
      for (int ks = 0; ks < 2; ks++) {
        int row = ni * 16 + l15;
        int ch = (ks * 4 + l4) ^ (row & 7);
        s16x8 kf = *(const s16x8*)(Ks + row * 64 + ch * 8);
        s = __builtin_amdgcn_mfma_f32_16x16x32_bf16(qf[ks], kf, s, 0, 0, 0);
      }
      sv[ni] = s * 0.125f;
    }
    if (kt == qt) {  // causal mask, diagonal tile only
#pragma unroll
      for (int ni = 0; ni < 4; ni++) {
        int tk = k0 + ni * 16 + l15;
#pragma unroll
        for (int r = 0; r < 4; r++) {
          int qr = q0 + wave * 16 + l4 * 4 + r;
          if (tk > qr) sv[ni][r] = -__builtin_inff();
        }
      }
    }
    // online softmax (rows live in 16-lane groups)
#pragma unroll
    for (int r = 0; r < 4; r++) {
      float mx = fmaxf(fmaxf(sv[0][r], sv[1][r]), fmaxf(sv[2][r], sv[3][r]));
#pragma unroll
      for (int off = 1; off < 16; off <<= 1) mx = fmaxf(mx, __shfl_xor(mx, off));
      float mn = fmaxf(m_r[r], mx);
      float sc = __builtin_amdgcn_exp2f((m_r[r] - mn) * L2E);
      m_r[r] = mn;
      float rs = 0.f;
#pragma unroll
      for (int ni = 0; ni < 4; ni++) {
        float p = __builtin_amdgcn_exp2f((sv[ni][r] - mn) * L2E);
        sv[ni][r] = p;
        rs += p;
      }
#pragma unroll
      for (int off = 1; off < 16; off <<= 1) rs += __shfl_xor(rs, off);
      l_r[r] = l_r[r] * sc + rs;
#pragma unroll
      for (int j = 0; j < 4; j++) acc_o[j][r] *= sc;
    }
    // P -> LDS bf16 (swizzled), C-layout -> A-fragment transpose
    char* Pw = (char*)&Ps[wave][0];
#pragma unroll
    for (int ni = 0; ni < 4; ni++)
#pragma unroll
      for (int r = 0; r < 4; r++) {
        int prow = l4 * 4 + r;
        int pcol = ni * 16 + l15;
        int sb = prow * 128 + (((pcol >> 3) ^ (prow & 7)) << 4) + ((pcol & 7) << 1);
        *(short*)(Pw + sb) = f2bf(sv[ni][r]);
      }
    // O += P V
#pragma unroll
    for (int ks = 0; ks < 2; ks++) {
      int pch = (ks * 4 + l4) ^ (l15 & 7);
      s16x8 pf = *(const s16x8*)(Pw + l15 * 128 + pch * 16);
#pragma unroll
      for (int ni = 0; ni < 4; ni++) {
        int d = ni * 16 + l15;
        int vch = (ks * 4 + l4) ^ (d & 7);
        s16x8 vf = *(const s16x8*)(Vs + d * 64 + vch * 8);
        acc_o[ni] = __builtin_amdgcn_mfma_f32_16x16x32_bf16(pf, vf, acc_o[ni], 0, 0, 0);
      }
    }
    __syncthreads();
  }
  // epilogue: Y[B,T,C] bf16
  const int b = bh >> 4, h = bh & 15;
#pragma unroll
  for (int r = 0; r < 4; r++) {
    float inv = 1.0f / l_r[r];
    int qr = q0 + wave * 16 + l4 * 4 + r;
    size_t base = ((size_t)b * 2048 + qr) * 1024 + h * 64;
#pragma unroll
    for (int j = 0; j < 4; j++) Y[base + j * 16 + l15] = f2bf(acc_o[j][r] * inv);
  }
}

extern "C" void kernel_launch(void* const* d_in, const int* in_sizes, int n_in,
                              void* d_out, int out_size, void* d_ws, size_t ws_size,
                              hipStream_t stream) {
  const float* x = (const float*)d_in[0];
  const float* Wq = (const float*)d_in[1];
  const float* bq = (const float*)d_in[2];
  const float* Wk = (const float*)d_in[3];
  const float* bk = (const float*)d_in[4];
  const float* Wv = (const float*)d_in[5];
  const float* bv = (const float*)d_in[6];
  const float* Wp = (const float*)d_in[7];
  const float* bp = (const float*)d_in[8];
  float* out = (float*)d_out;
  char* ws = (char*)d_ws;

  short* xb    = (short*)(ws + 0);         // 8 MB, reused as Y after QKV GEMM
  short* WqkvT = (short*)(ws + 8388608);   // 6 MB  [3072][1024]
  short* WpT   = (short*)(ws + 14680064);  // 2 MB
  short* Qb    = (short*)(ws + 16777216);  // 8 MB  [B,H,T,D]
  short* Kb    = (short*)(ws + 25165824);  // 8 MB
  short* Vtb   = (short*)(ws + 33554432);  // 8 MB  [B,H,D,T]
  short* Yb    = xb;

  cvt_bf16<<<2048, 256, 0, stream>>>(x, xb);
  transpose_w<<<dim3(16, 16), 256, 0, stream>>>(Wq, WqkvT);
  transpose_w<<<dim3(16, 16), 256, 0, stream>>>(Wk, WqkvT + 1048576);
  transpose_w<<<dim3(16, 16), 256, 0, stream>>>(Wv, WqkvT + 2097152);
  transpose_w<<<dim3(16, 16), 256, 0, stream>>>(Wp, WpT);
  gemm_bt<0><<<dim3(24, 32), 256, 0, stream>>>(xb, WqkvT, 3072, 1024, bq, bk, bv,
                                               Qb, Kb, Vtb, nullptr);
  attn64<<<dim3(32, 32), 256, 0, stream>>>(Qb, Kb, Vtb, Yb);
  gemm_bt<1><<<dim3(8, 32), 256, 0, stream>>>(Yb, WpT, 1024, 1024, bp, nullptr,
                                              nullptr, nullptr, nullptr, nullptr, out);
}

// Round 2
// 149.666 us; speedup vs baseline: 1.5434x; 1.5434x over previous
//
#include <hip/hip_runtime.h>
#include <cstdint>

typedef __attribute__((ext_vector_type(4))) short s16x4;
typedef __attribute__((ext_vector_type(8))) short s16x8;
typedef __attribute__((ext_vector_type(4))) float f32x4;
typedef __attribute__((ext_vector_type(16))) float f32x16;

#define L2E 1.44269504088896340736f

__device__ __forceinline__ short f2bf(float f) {
  union { float f; unsigned u; } v; v.f = f;
  unsigned r = (v.u + 0x7fffu + ((v.u >> 16) & 1u)) >> 16;
  return (short)r;
}

typedef const __attribute__((address_space(1))) unsigned int* gas_p;
typedef __attribute__((address_space(3))) unsigned int* las_p;
__device__ __forceinline__ void stage16(const void* g, void* l) {
  __builtin_amdgcn_global_load_lds((gas_p)(uintptr_t)g,
                                   (las_p)(unsigned int)(uintptr_t)l, 16, 0, 0);
}

// ---------------- fp32 -> bf16 convert (x) ----------------
__global__ __launch_bounds__(256) void cvt_bf16(const float* __restrict__ in,
                                                short* __restrict__ out) {
  int i = blockIdx.x * 256 + threadIdx.x;
  const f32x4* p = (const f32x4*)in + (size_t)i * 2;
  f32x4 a = p[0], b = p[1];
  s16x8 o;
  o[0] = f2bf(a[0]); o[1] = f2bf(a[1]); o[2] = f2bf(a[2]); o[3] = f2bf(a[3]);
  o[4] = f2bf(b[0]); o[5] = f2bf(b[1]); o[6] = f2bf(b[2]); o[7] = f2bf(b[3]);
  *((s16x8*)out + i) = o;
}

// ------------- transpose 1024x1024 fp32 -> bf16 [N][K] -------------
__global__ __launch_bounds__(256) void transpose_w(const float* __restrict__ in,
                                                   short* __restrict__ out) {
  __shared__ float tile[64][65];
  const int bi = blockIdx.y, bj = blockIdx.x;
  const int t = threadIdx.x;
  const int c = t & 63, r0 = t >> 6;
#pragma unroll
  for (int i = 0; i < 16; i++) {
    int r = r0 + i * 4;
    tile[r][c] = in[(size_t)(bi * 64 + r) * 1024 + bj * 64 + c];
  }
  __syncthreads();
#pragma unroll
  for (int i = 0; i < 16; i++) {
    int r = r0 + i * 4;
    out[(size_t)(bj * 64 + r) * 1024 + bi * 64 + c] = f2bf(tile[c][r]);
  }
}

// ---------------- GEMM: C[M,N] = A[M,K] * B[N,K]^T, bf16 in, fp32 acc ----------------
// EPI 0: fused QKV epilogue -> Q(*0.125)[B,H,T,D], K[B,H,T,D], V^T[B,H,D,T] bf16 (+bias)
// EPI 1: fp32 out row-major [M][N] (+bias)
template <int EPI>
__global__ __launch_bounds__(256) void gemm_bt(
    const short* __restrict__ A, const short* __restrict__ B, int N, int K,
    const float* __restrict__ b0, const float* __restrict__ b1,
    const float* __restrict__ b2, short* __restrict__ o0, short* __restrict__ o1,
    short* __restrict__ o2, float* __restrict__ ofp) {
  __shared__ short As[128 * 32];
  __shared__ short Bs[128 * 32];
  const int tid = threadIdx.x;
  const int lane = tid & 63;
  const int wave = tid >> 6;
  const int wr = wave >> 1, wc = wave & 1;
  const int l15 = lane & 15, l4 = lane >> 4;
  const int m0 = blockIdx.y * 128, n0 = blockIdx.x * 128;
  const short* Ab = A + (size_t)m0 * K;
  const short* Bb = B + (size_t)n0 * K;
  f32x4 acc[4][4];
#pragma unroll
  for (int i = 0; i < 4; i++)
#pragma unroll
    for (int j = 0; j < 4; j++) acc[i][j] = (f32x4){0.f, 0.f, 0.f, 0.f};

  const int srow = tid >> 2;
  const int sch = tid & 3;
  for (int k0 = 0; k0 < K; k0 += 32) {
    stage16(Ab + (size_t)srow * K + k0 + sch * 8, As + tid * 8);
    stage16(Ab + (size_t)(srow + 64) * K + k0 + sch * 8, As + 2048 + tid * 8);
    stage16(Bb + (size_t)srow * K + k0 + sch * 8, Bs + tid * 8);
    stage16(Bb + (size_t)(srow + 64) * K + k0 + sch * 8, Bs + 2048 + tid * 8);
    __syncthreads();
    s16x8 af[4], bfr[4];
#pragma unroll
    for (int i = 0; i < 4; i++) {
      af[i] = *(const s16x8*)(As + (wr * 64 + i * 16 + l15) * 32 + l4 * 8);
      bfr[i] = *(const s16x8*)(Bs + (wc * 64 + i * 16 + l15) * 32 + l4 * 8);
    }
#pragma unroll
    for (int mi = 0; mi < 4; mi++)
#pragma unroll
      for (int ni = 0; ni < 4; ni++)
        acc[mi][ni] = __builtin_amdgcn_mfma_f32_16x16x32_bf16(af[mi], bfr[ni],
                                                              acc[mi][ni], 0, 0, 0);
    __syncthreads();
  }

#pragma unroll
  for (int ni = 0; ni < 4; ni++) {
    const int col = n0 + wc * 64 + ni * 16 + l15;
    if (EPI == 1) {
      const float bias = b0[col];
#pragma unroll
      for (int mi = 0; mi < 4; mi++)
#pragma unroll
        for (int r = 0; r < 4; r++) {
          int row = m0 + wr * 64 + mi * 16 + l4 * 4 + r;
          ofp[(size_t)row * N + col] = acc[mi][ni][r] + bias;
        }
    } else {
      const float* bp; short* dst; int c1; int isV = 0; float scl = 1.0f;
      if (col < 1024) { bp = b0; dst = o0; c1 = col; scl = 0.125f; }
      else if (col < 2048) { bp = b1; dst = o1; c1 = col - 1024; }
      else { bp = b2; dst = o2; c1 = col - 2048; isV = 1; }
      const float bias = bp[c1];
      const int h = c1 >> 6, d = c1 & 63;
#pragma unroll
      for (int mi = 0; mi < 4; mi++)
#pragma unroll
        for (int r = 0; r < 4; r++) {
          int row = m0 + wr * 64 + mi * 16 + l4 * 4 + r;
          int bb = row >> 11, t = row & 2047;
          float v = (acc[mi][ni][r] + bias) * scl;
          size_t idx = isV ? ((size_t)((bb * 16 + h) * 64 + d) * 2048 + t)
                           : ((size_t)((bb * 16 + h) * 2048 + t) * 64 + d);
          dst[idx] = f2bf(v);
        }
    }
  }
}

// ------------- causal flash attention v2: swapped QK^T, 32x32 MFMA -------------
// 4 waves x 32 q-rows (QBLK=128), KVBLK=64, double-buffered K/V staging.
// S^T = mfma(K, Q): lane owns q = lane&31; kv per reg = (r&3)+8*(r>>2)+4*hi (+32*sub).
// O^T = mfma(V^T, P): acc col = q = lane&31 -> softmax stats stay lane-local.
__global__ __launch_bounds__(256) void attn_v2(const short* __restrict__ Q,
                                               const short* __restrict__ K,
                                               const short* __restrict__ Vt,
                                               short* __restrict__ Y) {
  __shared__ short Ks[2][64 * 64];  // [kv][d], 128B rows, chunk ^= (row&7) swizzle
  __shared__ short Vs[2][64 * 64];  // [d][kv], same swizzle
  const int bh = blockIdx.x;
  const int qt = (int)gridDim.y - 1 - blockIdx.y;  // heavy blocks dispatched first
  const int tid = threadIdx.x;
  const int lane = tid & 63, wave = tid >> 6;
  const int q31 = lane & 31, hi = lane >> 5;
  const short* Qp = Q + (size_t)bh * 2048 * 64;
  const short* Kp = K + (size_t)bh * 2048 * 64;
  const short* Vp = Vt + (size_t)bh * 64 * 2048;
  const int q0w = qt * 128 + wave * 32;
  const int qrow = q0w + q31;

  // Q B-fragments: qf[s] = Q[qrow][s*16 + hi*8 .. +8]  (Q pre-scaled by 0.125)
  s16x8 qf[4];
#pragma unroll
  for (int s = 0; s < 4; s++)
    qf[s] = *(const s16x8*)(Qp + (size_t)qrow * 64 + s * 16 + hi * 8);

  f32x16 accA, accB;  // O^T accumulators, d-subtiles 0 / 1
#pragma unroll
  for (int i = 0; i < 16; i++) { accA[i] = 0.f; accB[i] = 0.f; }
  float m = -__builtin_inff(), l = 0.f;

  const int srow = tid >> 3, sch = tid & 7;
  const int nt = 2 * qt + 2;                 // tiles the block stages
  const int ntw = 2 * qt + 1 + (wave >> 1);  // tiles this wave computes

  {  // prologue: stage tile 0 into buf 0 (LDS dest = wave-uniform + lane*16)
#pragma unroll
    for (int i = 0; i < 2; i++) {
      int row = srow + i * 32;
      int sc = sch ^ (row & 7);
      stage16(Kp + (size_t)row * 64 + sc * 8, &Ks[0][row * 64 + sch * 8]);
      stage16(Vp + (size_t)row * 2048 + sc * 8, &Vs[0][row * 64 + sch * 8]);
    }
  }
  __syncthreads();

  int buf = 0;
  for (int kt = 0; kt < nt; kt++) {
    if (kt + 1 < nt) {  // issue next-tile staging before compute (2-phase)
      const int k0n = (kt + 1) * 64;
#pragma unroll
      for (int i = 0; i < 2; i++) {
        int row = srow + i * 32;
        int sc = sch ^ (row & 7);
        stage16(Kp + (size_t)(k0n + row) * 64 + sc * 8, &Ks[buf ^ 1][row * 64 + sch * 8]);
        stage16(Vp + (size_t)row * 2048 + k0n + sc * 8, &Vs[buf ^ 1][row * 64 + sch * 8]);
      }
    }
    if (kt < ntw) {
      const int k0 = kt * 64;
      const short* Kb = &Ks[buf][0];
      const short* Vb = &Vs[buf][0];
      const int cx = (q31 & 7);
      // ---- S^T = K · Q  (two 32-kv subtiles) ----
      f32x16 s0, s1;
#pragma unroll
      for (int i = 0; i < 16; i++) { s0[i] = 0.f; s1[i] = 0.f; }
#pragma unroll
      for (int s = 0; s < 4; s++) {
        int c = (2 * s + hi) ^ cx;
        s16x8 kf0 = *(const s16x8*)(Kb + q31 * 64 + c * 8);
        s16x8 kf1 = *(const s16x8*)(Kb + (q31 + 32) * 64 + c * 8);
        s0 = __builtin_amdgcn_mfma_f32_32x32x16_bf16(kf0, qf[s], s0, 0, 0, 0);
        s1 = __builtin_amdgcn_mfma_f32_32x32x16_bf16(kf1, qf[s], s1, 0, 0, 0);
      }
      // ---- causal mask (diagonal region only) ----
      if (k0 + 63 > q0w) {
#pragma unroll
        for (int r = 0; r < 16; r++) {
          int kvr = k0 + (r & 3) + 8 * (r >> 2) + 4 * hi;
          if (kvr > qrow) s0[r] = -__builtin_inff();
          if (kvr + 32 > qrow) s1[r] = -__builtin_inff();
        }
      }
      // ---- online softmax: lane-local, one shfl per reduce ----
      float pmax = s0[0];
#pragma unroll
      for (int r = 1; r < 16; r++) pmax = fmaxf(pmax, s0[r]);
#pragma unroll
      for (int r = 0; r < 16; r++) pmax = fmaxf(pmax, s1[r]);
      pmax = fmaxf(pmax, __shfl_xor(pmax, 32));
      if (!__all(pmax <= m + 8.f)) {  // defer-max (T13)
        float mn = fmaxf(m, pmax);
        float sc_ = __builtin_amdgcn_exp2f((m - mn) * L2E);
        m = mn;
        l *= sc_;
#pragma unroll
        for (int i = 0; i < 16; i++) { accA[i] *= sc_; accB[i] *= sc_; }
      }
      const float mL2 = m * L2E;
      float rsum = 0.f;
#pragma unroll
      for (int r = 0; r < 16; r++) {
        float p = __builtin_amdgcn_exp2f(s0[r] * L2E - mL2);
        s0[r] = p; rsum += p;
      }
#pragma unroll
      for (int r = 0; r < 16; r++) {
        float p = __builtin_amdgcn_exp2f(s1[r] * L2E - mL2);
        s1[r] = p; rsum += p;
      }
      rsum += __shfl_xor(rsum, 32);
      l += rsum;
      // ---- P -> bf16 pairs in-register (T12) ----
      unsigned pk0[8], pk1[8];
#pragma unroll
      for (int j = 0; j < 8; j++) {
        unsigned r_;
        float a0 = s0[2 * j], a1 = s0[2 * j + 1];
        asm("v_cvt_pk_bf16_f32 %0, %1, %2" : "=v"(r_) : "v"(a0), "v"(a1));
        pk0[j] = r_;
        float b0 = s1[2 * j], b1 = s1[2 * j + 1];
        asm("v_cvt_pk_bf16_f32 %0, %1, %2" : "=v"(r_) : "v"(b0), "v"(b1));
        pk1[j] = r_;
      }
      // ---- O^T += V^T · P : build P B-frag via lane^32 exchange ----
#pragma unroll
      for (int s = 0; s < 4; s++) {
        const unsigned* pk = (s < 2) ? pk0 : pk1;  // compile-time after unroll
        const int s1i = s & 1;
        unsigned aA = hi ? pk[4 * s1i + 2] : pk[4 * s1i + 0];
        unsigned aB = hi ? pk[4 * s1i + 3] : pk[4 * s1i + 1];
        unsigned sA = hi ? pk[4 * s1i + 0] : pk[4 * s1i + 2];
        unsigned sB = hi ? pk[4 * s1i + 1] : pk[4 * s1i + 3];
        unsigned rA = __shfl_xor(sA, 32);
        unsigned rB = __shfl_xor(sB, 32);
        union { unsigned u[4]; s16x8 v; } fr;
        fr.u[0] = hi ? rA : aA;
        fr.u[1] = hi ? rB : aB;
        fr.u[2] = hi ? aA : rA;
        fr.u[3] = hi ? aB : rB;
        int c = (2 * s + hi) ^ cx;
        s16x8 vf0 = *(const s16x8*)(Vb + q31 * 64 + c * 8);
        s16x8 vf1 = *(const s16x8*)(Vb + (q31 + 32) * 64 + c * 8);
        accA = __builtin_amdgcn_mfma_f32_32x32x16_bf16(vf0, fr.v, accA, 0, 0, 0);
        accB = __builtin_amdgcn_mfma_f32_32x32x16_bf16(vf1, fr.v, accB, 0, 0, 0);
      }
    }
    __syncthreads();
    buf ^= 1;
  }
  // ---- epilogue: Y[B,T,C] bf16; lane holds q=qrow, d = (r&3)+8*(r>>2)+4*hi (+32) ----
  const int b_ = bh >> 4, h_ = bh & 15;
  const float invl = 1.f / l;
  const size_t base = ((size_t)b_ * 2048 + qrow) * 1024 + h_ * 64;
#pragma unroll
  for (int g = 0; g < 4; g++) {
    s16x4 o0, o1;
#pragma unroll
    for (int e = 0; e < 4; e++) {
      o0[e] = f2bf(accA[4 * g + e] * invl);
      o1[e] = f2bf(accB[4 * g + e] * invl);
    }
    *(s16x4*)(Y + base + 8 * g + 4 * hi) = o0;
    *(s16x4*)(Y + base + 32 + 8 * g + 4 * hi) = o1;
  }
}

extern "C" void kernel_launch(void* const* d_in, const int* in_sizes, int n_in,
                              void* d_out, int out_size, void* d_ws, size_t ws_size,
                              hipStream_t stream) {
  const float* x = (const float*)d_in[0];
  const float* Wq = (const float*)d_in[1];
  const float* bq = (const float*)d_in[2];
  const float* Wk = (const float*)d_in[3];
  const float* bk = (const float*)d_in[4];
  const float* Wv = (const float*)d_in[5];
  const float* bv = (const float*)d_in[6];
  const float* Wp = (const float*)d_in[7];
  const float* bp = (const float*)d_in[8];
  float* out = (float*)d_out;
  char* ws = (char*)d_ws;

  short* xb    = (short*)(ws + 0);         // 8 MB, reused as Y after QKV GEMM
  short* WqkvT = (short*)(ws + 8388608);   // 6 MB  [3072][1024]
  short* WpT   = (short*)(ws + 14680064);  // 2 MB
  short* Qb    = (short*)(ws + 16777216);  // 8 MB  [B,H,T,D] (pre-scaled by 0.125)
  short* Kb    = (short*)(ws + 25165824);  // 8 MB  [B,H,T,D]
  short* Vtb   = (short*)(ws + 33554432);  // 8 MB  [B,H,D,T]
  short* Yb    = xb;

  cvt_bf16<<<2048, 256, 0, stream>>>(x, xb);
  transpose_w<<<dim3(16, 16), 256, 0, stream>>>(Wq, WqkvT);
  transpose_w<<<dim3(16, 16), 256, 0, stream>>>(Wk, WqkvT + 1048576);
  transpose_w<<<dim3(16, 16), 256, 0, stream>>>(Wv, WqkvT + 2097152);
  transpose_w<<<dim3(16, 16), 256, 0, stream>>>(Wp, WpT);
  gemm_bt<0><<<dim3(24, 32), 256, 0, stream>>>(xb, WqkvT, 3072, 1024, bq, bk, bv,
                                               Qb, Kb, Vtb, nullptr);
  attn_v2<<<dim3(32, 16), 256, 0, stream>>>(Qb, Kb, Vtb, Yb);
  gemm_bt<1><<<dim3(8, 32), 256, 0, stream>>>(Yb, WpT, 1024, 1024, bp, nullptr,
                                              nullptr, nullptr, nullptr, nullptr, out);
}